// Round 2
// baseline (643.253 us; speedup 1.0000x reference)
//
#include <hip/hip_runtime.h>
#include <hip/hip_bf16.h>
#include <stdint.h>

// Swin window-attention, MI355X.
//  cvt_w -> gemm_bt<0> (x -> QKV, gather fused) -> attn -> gemm_bt<1> (proj + scatter)

typedef __bf16 v8bf __attribute__((ext_vector_type(8)));
typedef __bf16 v4bf __attribute__((ext_vector_type(4)));
typedef float  v4f  __attribute__((ext_vector_type(4)));

#define MFMA16(a,b,c) __builtin_amdgcn_mfma_f32_16x16x32_bf16(a,b,c,0,0,0)

typedef const void __attribute__((address_space(1))) gas_t;
typedef void __attribute__((address_space(3))) las_t;
__device__ __forceinline__ void gl2lds16(const void* g, void* l) {
  __builtin_amdgcn_global_load_lds((gas_t*)g, (las_t*)l, 16, 0, 0);
}

// ---------------- weight conversion f32->bf16 ----------------
__global__ __launch_bounds__(256) void cvt_w_kernel(const float* __restrict__ qw,
                                                    const float* __restrict__ pw,
                                                    __bf16* __restrict__ dq,
                                                    __bf16* __restrict__ dp) {
  uint32_t cid = blockIdx.x * 256u + threadIdx.x;          // < 147456
  uint32_t e = cid * 4u;
  const float* src; __bf16* dst; uint32_t off;
  if (e < 442368u) { src = qw; dst = dq; off = e; }
  else             { src = pw; dst = dp; off = e - 442368u; }
  float4 v = *(const float4*)(src + off);
  v4bf o; o[0] = (__bf16)v.x; o[1] = (__bf16)v.y; o[2] = (__bf16)v.z; o[3] = (__bf16)v.w;
  *(v4bf*)(dst + off) = o;
}

// ---------------- BT GEMM: C[m,n] = sum_k A[m,k]*B[n,k] + bias, K=384, BK=64 ----------------
// 128x128 tile, 4 waves, XOR-swizzled LDS (st-style: 16B unit ^= row&7).
// EPI 0: A comes directly from x (roll -3,-3 + window partition + f32->bf16 fused
//        via reg staging); C -> QKV[m][1152] bf16 (unscaled; attn applies hd^-0.5).
// EPI 1: A = attn-out bf16 [m][384] via global_load_lds (pre-swizzled source);
//        epilogue scatters f32 with window-reverse + roll(+3,+3).
template<int EPI>
__global__ __launch_bounds__(256) void gemm_bt(const float* __restrict__ Xf,
                                               const __bf16* __restrict__ Abf,
                                               const __bf16* __restrict__ Bw,
                                               const float* __restrict__ biasv,
                                               __bf16* __restrict__ Cbf,
                                               float* __restrict__ Of) {
  constexpr uint32_t NT = (EPI == 0) ? 9u : 3u;
  __shared__ __bf16 lds_a[128 * 64];
  __shared__ __bf16 lds_b[128 * 64];
  __shared__ uint32_t rowbase[128];
  const int tid = threadIdx.x, wv = tid >> 6, ln = tid & 63;
  const int wr = wv >> 1, wc = wv & 1;
  const int c = ln & 15, rq = (ln >> 4) * 4;
  // XCD-chunked bijective swizzle, n-fast: all NT n-tiles of one m-tile -> same XCD.
  const uint32_t chunk = gridDim.x >> 3;
  const uint32_t phys = blockIdx.x;
  const uint32_t lbid = (phys & 7u) * chunk + (phys >> 3);
  const uint32_t mt = lbid / NT, nt = lbid - mt * NT;
  const uint32_t m0 = mt * 128u, n0 = nt * 128u;

  if (EPI == 0) {
    if (tid < 128) {                                   // gather mapping, once per block
      uint32_t mg = m0 + tid;
      uint32_t win = mg / 49u, tok = mg - win * 49u;
      uint32_t b = win >> 6, wy = (win >> 3) & 7u, wx = win & 7u;
      uint32_t ty = tok / 7u, tx = tok - ty * 7u;
      uint32_t sy = wy * 7u + ty + 3u; if (sy >= 56u) sy -= 56u;
      uint32_t sx = wx * 7u + tx + 3u; if (sx >= 56u) sx -= 56u;
      rowbase[tid] = ((b * 56u + sy) * 56u + sx) * 384u;
    }
    __syncthreads();
  }

  v4f acc[4][4] = {};
  for (int ks = 0; ks < 6; ++ks) {
    const uint32_t k0 = ks * 64u;
    // B (and A for EPI1): global_load_lds, source pre-swizzled so LDS holds
    // 16B-unit u at linear slot u^(row&7)  (dest is linear: base + lane*16).
#pragma unroll
    for (int t = 0; t < 4; ++t) {
      const int ch = wv + 4 * t;                       // wave-uniform chunk id
      uint32_t row = (uint32_t)ch * 8u + (uint32_t)(ln >> 3);
      uint32_t u = ((uint32_t)(ln & 7)) ^ (row & 7u);
      gl2lds16(Bw + (size_t)(n0 + row) * 384u + k0 + u * 8u, lds_b + ch * 512);
      if (EPI == 1)
        gl2lds16(Abf + (size_t)(m0 + row) * 384u + k0 + u * 8u, lds_a + ch * 512);
    }
    if (EPI == 0) {
      // A from x: 8 passes x (float4 load -> cvt -> swizzled ds_write 8B)
      const uint32_t arow = (uint32_t)(tid >> 4);
      const uint32_t acol = (uint32_t)(tid & 15) * 4u;
      float4 f[8];
#pragma unroll
      for (int p = 0; p < 8; ++p)
        f[p] = *(const float4*)(Xf + rowbase[p * 16 + arow] + k0 + acol);
#pragma unroll
      for (int p = 0; p < 8; ++p) {
        uint32_t row = (uint32_t)p * 16u + arow;
        v4bf o; o[0] = (__bf16)f[p].x; o[1] = (__bf16)f[p].y;
        o[2] = (__bf16)f[p].z; o[3] = (__bf16)f[p].w;
        uint32_t byt = (row << 7) + ((acol * 2u) ^ ((row & 7u) << 4));
        *(v4bf*)((char*)lds_a + byt) = o;
      }
    }
    __syncthreads();
#pragma unroll
    for (int kk = 0; kk < 2; ++kk) {
      v8bf af[4], bfr[4];
#pragma unroll
      for (int mi = 0; mi < 4; ++mi) {
        uint32_t row = (uint32_t)(wr * 64 + mi * 16 + c);
        uint32_t byt = (row << 7) + (((uint32_t)(kk * 64 + rq * 4)) ^ ((row & 7u) << 4));
        af[mi] = *(const v8bf*)((char*)lds_a + byt);
      }
#pragma unroll
      for (int ni = 0; ni < 4; ++ni) {
        uint32_t row = (uint32_t)(wc * 64 + ni * 16 + c);
        uint32_t byt = (row << 7) + (((uint32_t)(kk * 64 + rq * 4)) ^ ((row & 7u) << 4));
        bfr[ni] = *(const v8bf*)((char*)lds_b + byt);
      }
#pragma unroll
      for (int mi = 0; mi < 4; ++mi)
#pragma unroll
        for (int ni = 0; ni < 4; ++ni)
          acc[mi][ni] = MFMA16(af[mi], bfr[ni], acc[mi][ni]);
    }
    __syncthreads();
  }

  if (EPI == 0) {
#pragma unroll
    for (int ni = 0; ni < 4; ++ni) {
      uint32_t colg = n0 + wc * 64u + ni * 16u + c;
      float bv = biasv[colg];
#pragma unroll
      for (int mi = 0; mi < 4; ++mi) {
        uint32_t mg = m0 + wr * 64u + mi * 16u + rq;
#pragma unroll
        for (int r = 0; r < 4; ++r)
          Cbf[(size_t)(mg + r) * 1152u + colg] = (__bf16)(acc[mi][ni][r] + bv);
      }
    }
  } else {
#pragma unroll
    for (int ni = 0; ni < 4; ++ni) {
      uint32_t colg = n0 + wc * 64u + ni * 16u + c;
      float bv = biasv[colg];
#pragma unroll
      for (int mi = 0; mi < 4; ++mi)
#pragma unroll
        for (int r = 0; r < 4; ++r) {
          uint32_t mg = m0 + wr * 64u + mi * 16u + rq + r;
          uint32_t win = mg / 49u, tok = mg - win * 49u;
          uint32_t b = win >> 6, wy = (win >> 3) & 7u, wx = win & 7u;
          uint32_t ty = tok / 7u, tx = tok - ty * 7u;
          uint32_t y = wy * 7u + ty + 3u; if (y >= 56u) y -= 56u;
          uint32_t x = wx * 7u + tx + 3u; if (x >= 56u) x -= 56u;
          Of[(((size_t)b * 56u + y) * 56u + x) * 384u + colg] = acc[mi][ni][r] + bv;
        }
    }
  }
}

// ---------------- fused window attention: one wave per (window, head) ----------------
// QKV merged layout [win*49+tok][1152]: q at +0, k at +384, v at +768 (per head*32).
// S^T = K @ Q^T (scaled in f32), bias+mask inline, in-register softmax over keys,
// P via per-wave LDS, O^T = V^T @ P^T. Row indices clamped to 48 (no overread).
__global__ __launch_bounds__(256) void attn_kernel(const __bf16* __restrict__ QKV,
                                                   const float* __restrict__ rpb,
                                                   __bf16* __restrict__ Oa) {
  __shared__ __bf16 plds[4][64 * 72];
  const int tid = threadIdx.x, wv = tid >> 6, ln = tid & 63;
  const int c = ln & 15, rq = (ln >> 4) * 4;
  const uint32_t gwh = blockIdx.x * 4u + wv;           // < 24576
  const uint32_t win = gwh / 12u, head = gwh - win * 12u;
  const uint32_t wy = (win >> 3) & 7u, wx = win & 7u;
  const __bf16* qb = QKV + (size_t)win * 49u * 1152u + head * 32u;
  const __bf16* kb = qb + 384;
  const __bf16* vb = qb + 768;

  v8bf qf[4], kf[4];
#pragma unroll
  for (int t = 0; t < 4; ++t) {
    int rr = t * 16 + c; if (rr > 48) rr = 48;         // clamp (dup row 48)
    qf[t] = *(const v8bf*)(qb + (size_t)rr * 1152u + rq * 2);
    kf[t] = *(const v8bf*)(kb + (size_t)rr * 1152u + rq * 2);
  }
  v4f st[4][4] = {};                                   // S^T[jt][it]: row j(key), col i(query)
#pragma unroll
  for (int jt = 0; jt < 4; ++jt)
#pragma unroll
    for (int it = 0; it < 4; ++it)
      st[jt][it] = MFMA16(kf[jt], qf[it], st[jt][it]);

  // --- scale + bias + shift-mask ---
  const float scl = 0.17677669529663687f;              // hd^-0.5
  int iy[4], ix[4], icls[4];
#pragma unroll
  for (int it = 0; it < 4; ++it) {
    int ii = it * 16 + c; if (ii > 48) ii = 48;
    int y = ii / 7, x = ii - y * 7;
    iy[it] = y; ix[it] = x;
    int cy = (wy == 7u) ? ((y < 4) ? 1 : 2) : 0;
    int cx = (wx == 7u) ? ((x < 4) ? 1 : 2) : 0;
    icls[it] = cy * 3 + cx;
  }
#pragma unroll
  for (int jt = 0; jt < 4; ++jt)
#pragma unroll
    for (int r = 0; r < 4; ++r) {
      int j = jt * 16 + rq + r;
      int jc = j > 48 ? 48 : j;
      int jy = jc / 7, jx = jc - jy * 7;
      int cy = (wy == 7u) ? ((jy < 4) ? 1 : 2) : 0;
      int cx = (wx == 7u) ? ((jx < 4) ? 1 : 2) : 0;
      int jcls = cy * 3 + cx;
      bool jvalid = (j < 49);
#pragma unroll
      for (int it = 0; it < 4; ++it) {
        float s = st[jt][it][r];
        if (jvalid) {
          int idx = ((iy[it] - jy + 6) * 13 + (ix[it] - jx + 6)) * 12 + (int)head;
          s = s * scl + rpb[idx] + ((icls[it] == jcls) ? 0.f : -100.f);
        } else s = -1e30f;
        st[jt][it][r] = s;
      }
    }

  // --- softmax over j, per column i ---
  float rinv[4];
#pragma unroll
  for (int it = 0; it < 4; ++it) {
    float m = -1e30f;
#pragma unroll
    for (int jt = 0; jt < 4; ++jt)
#pragma unroll
      for (int r = 0; r < 4; ++r) m = fmaxf(m, st[jt][it][r]);
    m = fmaxf(m, __shfl_xor(m, 16));
    m = fmaxf(m, __shfl_xor(m, 32));
    float sum = 0.f;
#pragma unroll
    for (int jt = 0; jt < 4; ++jt)
#pragma unroll
      for (int r = 0; r < 4; ++r) {
        float p = __expf(st[jt][it][r] - m);
        st[jt][it][r] = p; sum += p;
      }
    sum += __shfl_xor(sum, 16);
    sum += __shfl_xor(sum, 32);
    rinv[it] = 1.0f / sum;
  }

  // --- P -> LDS (row-major [i][j], pad 72) ---
  __bf16* pw = plds[wv];
#pragma unroll
  for (int jt = 0; jt < 4; ++jt)
#pragma unroll
    for (int it = 0; it < 4; ++it) {
      v4bf pk;
#pragma unroll
      for (int r = 0; r < 4; ++r) pk[r] = (__bf16)st[jt][it][r];
      *(v4bf*)(pw + (it * 16 + c) * 72 + jt * 16 + rq) = pk;
    }

  // --- O^T = V^T @ P^T ---
  v4f ot[2][4] = {};
#pragma unroll
  for (int ks2 = 0; ks2 < 2; ++ks2) {
    v8bf av[2];
#pragma unroll
    for (int m16 = 0; m16 < 2; ++m16)
#pragma unroll
      for (int jj = 0; jj < 8; ++jj) {
        int tok = ks2 * 32 + rq * 2 + jj; if (tok > 48) tok = 48;
        av[m16][jj] = vb[(size_t)tok * 1152u + m16 * 16 + c];
      }
#pragma unroll
    for (int it = 0; it < 4; ++it) {
      v8bf pf = *(const v8bf*)(pw + (it * 16 + c) * 72 + ks2 * 32 + rq * 2);
#pragma unroll
      for (int m16 = 0; m16 < 2; ++m16)
        ot[m16][it] = MFMA16(av[m16], pf, ot[m16][it]);
    }
  }

  // --- store O: Oa[win*49+i][head*32+d] bf16 ---
#pragma unroll
  for (int it = 0; it < 4; ++it) {
    int i = it * 16 + c;
    if (i < 49) {
      float ri = rinv[it];
#pragma unroll
      for (int m16 = 0; m16 < 2; ++m16) {
        v4bf o;
#pragma unroll
        for (int r = 0; r < 4; ++r) o[r] = (__bf16)(ot[m16][it][r] * ri);
        *(v4bf*)(Oa + ((size_t)win * 49u + i) * 384u + head * 32u + m16 * 16 + rq) = o;
      }
    }
  }
}

// ---------------- launch ----------------
extern "C" void kernel_launch(void* const* d_in, const int* in_sizes, int n_in,
                              void* d_out, int out_size, void* d_ws, size_t ws_size,
                              hipStream_t stream) {
  const float* x      = (const float*)d_in[0];
  const float* qkv_w  = (const float*)d_in[1];
  const float* qkv_b  = (const float*)d_in[2];
  const float* proj_w = (const float*)d_in[3];
  const float* proj_b = (const float*)d_in[4];
  const float* rpb    = (const float*)d_in[5];
  float* out = (float*)d_out;

  char* w = (char*)d_ws;
  __bf16* Aout = (__bf16*)(w);                         //  77,070,336 B (attn out, [m][384])
  __bf16* Wq   = (__bf16*)(w + 77070336);              //     884,736 B
  __bf16* Wp   = (__bf16*)(w + 77955072);              //     294,912 B
  __bf16* QKV  = (__bf16*)(w + 78250240);              // 231,211,008 B ([m][1152])
                                                       // total 309,461,248 B

  cvt_w_kernel<<<576, 256, 0, stream>>>(qkv_w, proj_w, Wq, Wp);
  gemm_bt<0><<<7056, 256, 0, stream>>>(x, nullptr, Wq, qkv_b, QKV, nullptr);
  attn_kernel<<<6144, 256, 0, stream>>>(QKV, rpb, Aout);
  gemm_bt<1><<<2352, 256, 0, stream>>>(nullptr, Aout, Wp, proj_b, nullptr, out);
}